// Round 1
// 300.399 us; speedup vs baseline: 1.0159x; 1.0159x over previous
//
#include <hip/hip_runtime.h>
#include <hip/hip_bf16.h>
#include <stdint.h>

#define BN_EPS 1e-5f
#define NSTRIPE 64

typedef __attribute__((ext_vector_type(8)))  short bf16x8;
typedef __attribute__((ext_vector_type(16))) float f32x16;

static __device__ __forceinline__ float bflo2f(uint32_t p){
  union { uint32_t u; float f; } c; c.u = p << 16; return c.f;
}
static __device__ __forceinline__ float bfhi2f(uint32_t p){
  union { uint32_t u; float f; } c; c.u = p & 0xffff0000u; return c.f;
}
static __device__ __forceinline__ uint16_t f2bf(float f){
  union { float f; uint32_t u; } c; c.f = f;
  uint32_t u = c.u;
  return (uint16_t)((u + 0x7fffu + ((u >> 16) & 1u)) >> 16);
}
static __device__ __forceinline__ uint32_t pack2(float a, float b){
  return (uint32_t)f2bf(a) | ((uint32_t)f2bf(b) << 16);
}

// ---- prepass: h fp32->bf16 | W transpose (plain [n][k] bf16) | zero striped stats | dst histogram ----
__global__ void k_prep(const float* __restrict__ h, uint16_t* __restrict__ hb, int hblocks,
                       const float* __restrict__ W1, const float* __restrict__ W2,
                       uint16_t* __restrict__ Wt1, uint16_t* __restrict__ Wt2,
                       float* __restrict__ stats,
                       const int* __restrict__ dst, int* __restrict__ M, int E, int NB){
  int b = blockIdx.x, t = threadIdx.x;
  if (b < hblocks){
    int i = (b * 256 + t) * 8;
    float4 a = *(const float4*)(h + i);
    float4 bb = *(const float4*)(h + i + 4);
    uint4 o;
    o.x = pack2(a.x, a.y); o.y = pack2(a.z, a.w);
    o.z = pack2(bb.x, bb.y); o.w = pack2(bb.z, bb.w);
    *(uint4*)(hb + i) = o;
    return;
  }
  if (b < hblocks + 16){
    int gid = (b - hblocks) * 256 + t;   // 0..4095
    { // zero striped stats: 4 arrays * 64 stripes * 128 cols = 32768 floats
      float4 z = make_float4(0.f, 0.f, 0.f, 0.f);
      *(float4*)(stats + gid * 8) = z;
      *(float4*)(stats + gid * 8 + 4) = z;
    }
    const float* Wf = (gid < 2048) ? W1 : W2;
    uint16_t* Wt = (gid < 2048) ? Wt1 : Wt2;
    int cid = gid & 2047;
    int nrow = cid >> 4;
    int c    = cid & 15;
    int k0 = c * 8;
    float e[8];
    #pragma unroll
    for (int j = 0; j < 8; ++j) e[j] = Wf[(k0 + j) * 128 + nrow];
    uint4 o;
    o.x = pack2(e[0], e[1]); o.y = pack2(e[2], e[3]);
    o.z = pack2(e[4], e[5]); o.w = pack2(e[6], e[7]);
    *(uint4*)(Wt + nrow * 128 + c * 8) = o;   // plain layout (B read from global)
    return;
  }
  // histogram chunk
  int eb = b - hblocks - 16;
  __shared__ int cnt[512];
  cnt[t] = 0; cnt[t + 256] = 0;
  __syncthreads();
  int base = eb * 4096;
  #pragma unroll 4
  for (int j = t; j < 4096; j += 256){
    int i = base + j;
    if (i < E) atomicAdd(&cnt[dst[i] >> 8], 1);
  }
  __syncthreads();
  size_t row = (size_t)eb * NB;
  if (t < NB) M[row + t] = cnt[t];
  int t2 = t + 256;
  if (t2 < NB) M[row + t2] = cnt[t2];
}

// ---------------- CSR chain ----------------
__global__ void k_colscan(int* __restrict__ M, int* __restrict__ btot, int EB, int NB){
  __shared__ int s[256];
  int b = blockIdx.x, t = threadIdx.x;
  int i0 = 2 * t, i1 = 2 * t + 1;
  int v0 = (i0 < EB) ? M[(size_t)i0 * NB + b] : 0;
  int v1 = (i1 < EB) ? M[(size_t)i1 * NB + b] : 0;
  s[t] = v0 + v1;
  __syncthreads();
  for (int off = 1; off < 256; off <<= 1){
    int v = (t >= off) ? s[t - off] : 0;
    __syncthreads();
    s[t] += v;
    __syncthreads();
  }
  int excl = s[t] - (v0 + v1);
  if (i0 < EB) M[(size_t)i0 * NB + b] = excl;
  if (i1 < EB) M[(size_t)i1 * NB + b] = excl + v0;
  if (t == 255) btot[b] = s[255];
}

__global__ void k_bscan(const int* __restrict__ btot, int* __restrict__ bbase,
                        int* __restrict__ row_off, int NB, int n, int E){
  __shared__ int s[256];
  int t = threadIdx.x;
  int i0 = 2 * t, i1 = 2 * t + 1;
  int v0 = (i0 < NB) ? btot[i0] : 0;
  int v1 = (i1 < NB) ? btot[i1] : 0;
  s[t] = v0 + v1;
  __syncthreads();
  for (int off = 1; off < 256; off <<= 1){
    int v = (t >= off) ? s[t - off] : 0;
    __syncthreads();
    s[t] += v;
    __syncthreads();
  }
  int excl = s[t] - (v0 + v1);
  if (i0 < NB) bbase[i0] = excl;
  if (i1 < NB) bbase[i1] = excl + v0;
  if (t == 0){ bbase[NB] = E; row_off[n] = E; }
}

// binned entry: low 24 bits = src node id (N < 2^24), high 8 bits = dst & 255
__global__ void k_bin(const int* __restrict__ src, const int* __restrict__ dst,
                      const int* __restrict__ M, const int* __restrict__ bbase,
                      uint32_t* __restrict__ binned, int E, int NB){
  __shared__ int comb[512];
  __shared__ int cur[512];
  int t = threadIdx.x;
  size_t row = (size_t)blockIdx.x * NB;
  if (t < NB) comb[t] = bbase[t] + M[row + t];
  int t2 = t + 256;
  if (t2 < NB) comb[t2] = bbase[t2] + M[row + t2];
  cur[t] = 0; cur[t + 256] = 0;
  __syncthreads();
  int base = blockIdx.x * 4096;
  #pragma unroll 4
  for (int j = t; j < 4096; j += 256){
    int i = base + j;
    if (i < E){
      int d = dst[i];
      int b = d >> 8;
      int r = atomicAdd(&cur[b], 1);
      binned[comb[b] + r] = (uint32_t)src[i] | ((uint32_t)(d & 255) << 24);
    }
  }
}

__global__ void k_csr(const uint32_t* __restrict__ binned, const int* __restrict__ bbase,
                      int* __restrict__ row_off, int* __restrict__ col_idx, int n){
  __shared__ int cnt[256];
  __shared__ int off[256];
  __shared__ int cur[256];
  int b = blockIdx.x, t = threadIdx.x;
  int e0 = bbase[b], e1 = bbase[b + 1];
  int nb0 = b << 8;
  cnt[t] = 0; cur[t] = 0;
  __syncthreads();
  int m = e1 - e0;
  for (int j = t; j < m; j += 256) atomicAdd(&cnt[binned[e0 + j] >> 24], 1);
  __syncthreads();
  int v = cnt[t];
  off[t] = v;
  __syncthreads();
  for (int o = 1; o < 256; o <<= 1){
    int u = (t >= o) ? off[t - o] : 0;
    __syncthreads();
    off[t] += u;
    __syncthreads();
  }
  int excl = off[t] - v;
  __syncthreads();
  off[t] = excl;
  if (nb0 + t < n) row_off[nb0 + t] = e0 + excl;
  __syncthreads();
  for (int j = t; j < m; j += 256){
    uint32_t p = binned[e0 + j];
    int dl = (int)(p >> 24);
    int r = atomicAdd(&cur[dl], 1);
    col_idx[e0 + off[dl] + r] = (int)(p & 0xFFFFFFu);
  }
}

// -------- fused gather + GEMM1: 16-lane group owns one row, 8-edge-deep pipelined gather --------
__global__ __launch_bounds__(256, 4) void k_gg(
    const uint16_t* __restrict__ hb, const int* __restrict__ row_off,
    const int* __restrict__ col_idx, const float* __restrict__ eps_p,
    const uint16_t* __restrict__ Wt, const float* __restrict__ bias_f,
    uint16_t* __restrict__ Yout, float* __restrict__ osum_s, float* __restrict__ osq_s, int n){
  __shared__ __align__(16) uint16_t Al[64 * 128];   // 16 KB, swizzled; reused as Y tile
  __shared__ float csum[128], csq[128];
  int tid = threadIdx.x;
  int rbase = blockIdx.x * 64;
  int stripe = blockIdx.x & (NSTRIPE - 1);
  int grp = tid >> 4;       // 0..15: group owns one row at a time
  int c   = tid & 15;       // 8-feature chunk within the row
  const uint4* hp4 = (const uint4*)hb;
  float ce = 1.0f + eps_p[0];
  if (tid < 128){ csum[tid] = 0.f; csq[tid] = 0.f; }

  // ---- gather phase: 16 rows in flight per block, no cross-lane reduce needed ----
  for (int it = 0; it < 4; ++it){
    int m = it * 16 + grp;
    int gr = rbase + m;
    float a0=0.f,a1=0.f,a2=0.f,a3=0.f,a4=0.f,a5=0.f,a6=0.f,a7=0.f;
    if (gr < n){
      int j = row_off[gr], jend = row_off[gr + 1];
      // main loop: 8 independent gathers in flight per lane
      for (; j + 8 <= jend; j += 8){
        int s[8];
        #pragma unroll
        for (int e = 0; e < 8; ++e) s[e] = col_idx[j + e];
        uint4 v[8];
        #pragma unroll
        for (int e = 0; e < 8; ++e) v[e] = hp4[(size_t)s[e] * 16 + c];
        #pragma unroll
        for (int e = 0; e < 8; ++e){
          a0 += bflo2f(v[e].x); a1 += bfhi2f(v[e].x);
          a2 += bflo2f(v[e].y); a3 += bfhi2f(v[e].y);
          a4 += bflo2f(v[e].z); a5 += bfhi2f(v[e].z);
          a6 += bflo2f(v[e].w); a7 += bfhi2f(v[e].w);
        }
      }
      // masked tail round (dup-address gathers coalesce; weight 0 kills them)
      if (j < jend){
        int s[8]; float wq[8];
        #pragma unroll
        for (int e = 0; e < 8; ++e){
          int jj = j + e;
          wq[e] = (jj < jend) ? 1.f : 0.f;
          s[e] = col_idx[(jj < jend) ? jj : (jend - 1)];
        }
        uint4 v[8];
        #pragma unroll
        for (int e = 0; e < 8; ++e) v[e] = hp4[(size_t)s[e] * 16 + c];
        #pragma unroll
        for (int e = 0; e < 8; ++e){
          a0 = fmaf(wq[e], bflo2f(v[e].x), a0); a1 = fmaf(wq[e], bfhi2f(v[e].x), a1);
          a2 = fmaf(wq[e], bflo2f(v[e].y), a2); a3 = fmaf(wq[e], bfhi2f(v[e].y), a3);
          a4 = fmaf(wq[e], bflo2f(v[e].z), a4); a5 = fmaf(wq[e], bfhi2f(v[e].z), a5);
          a6 = fmaf(wq[e], bflo2f(v[e].w), a6); a7 = fmaf(wq[e], bfhi2f(v[e].w), a7);
        }
      }
      // self term (eps combine)
      uint4 vh = hp4[(size_t)gr * 16 + c];
      a0 = fmaf(ce, bflo2f(vh.x), a0); a1 = fmaf(ce, bfhi2f(vh.x), a1);
      a2 = fmaf(ce, bflo2f(vh.y), a2); a3 = fmaf(ce, bfhi2f(vh.y), a3);
      a4 = fmaf(ce, bflo2f(vh.z), a4); a5 = fmaf(ce, bfhi2f(vh.z), a5);
      a6 = fmaf(ce, bflo2f(vh.w), a6); a7 = fmaf(ce, bfhi2f(vh.w), a7);
    }
    uint4 o;
    o.x = pack2(a0, a1); o.y = pack2(a2, a3);
    o.z = pack2(a4, a5); o.w = pack2(a6, a7);
    *(uint4*)((char*)Al + m * 256 + ((c ^ (m & 15)) * 16)) = o;
  }
  __syncthreads();

  // ---- MFMA phase: A from LDS (swizzled), B straight from global (L2-hot) ----
  int lane = tid & 63;
  int w    = tid >> 6;
  int hi   = lane >> 5;
  int key  = lane & 15;
  int m0   = (w & 1) * 32;
  int n0   = (w >> 1) * 64;
  int mrow = m0 + (lane & 31);
  int nrow0 = n0 + (lane & 31);
  int nrow1 = nrow0 + 32;

  f32x16 acc0, acc1;
  #pragma unroll
  for (int i = 0; i < 16; ++i){ acc0[i] = 0.f; acc1[i] = 0.f; }

  const char* Ab = (const char*)Al;
  #pragma unroll
  for (int kt = 0; kt < 8; ++kt){
    int ck = 2 * kt + hi;
    bf16x8 a  = *(const bf16x8*)(Ab + mrow * 256 + ((ck ^ key) * 16));
    bf16x8 b0 = *(const bf16x8*)(Wt + nrow0 * 128 + ck * 8);
    bf16x8 b1 = *(const bf16x8*)(Wt + nrow1 * 128 + ck * 8);
    acc0 = __builtin_amdgcn_mfma_f32_32x32x16_bf16(a, b0, acc0, 0, 0, 0);
    acc1 = __builtin_amdgcn_mfma_f32_32x32x16_bf16(a, b1, acc1, 0, 0, 0);
  }
  __syncthreads();   // all a-frag reads done; reuse Al as Y tile

  uint16_t* Yl = Al;
  float bias0 = bias_f[nrow0];
  float bias1 = bias_f[nrow1];
  float ps0 = 0.f, pq0 = 0.f, ps1 = 0.f, pq1 = 0.f;
  #pragma unroll
  for (int r = 0; r < 16; ++r){
    int row = m0 + (r & 3) + 8 * (r >> 2) + 4 * hi;
    bool valid = (rbase + row) < n;
    float y0 = acc0[r] + bias0;
    float y1 = acc1[r] + bias1;
    if (valid){
      ps0 += y0; pq0 += y0 * y0;
      ps1 += y1; pq1 += y1 * y1;
    }
    Yl[row * 128 + nrow0] = f2bf(y0);
    Yl[row * 128 + nrow1] = f2bf(y1);
  }
  atomicAdd(&csum[nrow0], ps0); atomicAdd(&csq[nrow0], pq0);
  atomicAdd(&csum[nrow1], ps1); atomicAdd(&csq[nrow1], pq1);
  __syncthreads();

  #pragma unroll
  for (int i = 0; i < 4; ++i){
    int id = tid + 256 * i;
    int row = id >> 4, cc = id & 15;
    int gr = rbase + row;
    if (gr < n)
      *((uint4*)Yout + (size_t)gr * 16 + cc) = *((const uint4*)Yl + id);
  }
  if (tid < 128){
    atomicAdd(&osum_s[stripe * 128 + tid], csum[tid]);
    atomicAdd(&osq_s[stripe * 128 + tid], csq[tid]);
  }
}

// -------- GEMM2: BN1(from stripes)+ReLU on input, MFMA (B from global), striped stats out --------
__global__ __launch_bounds__(256, 4) void k_mgemm2(
    const uint16_t* __restrict__ Ag, const uint16_t* __restrict__ Wt,
    const float* __restrict__ bias_f,
    const float* __restrict__ sin_s, const float* __restrict__ sqin_s,
    const float* __restrict__ gin, const float* __restrict__ bein, float invN,
    uint16_t* __restrict__ Yout, float* __restrict__ osum_s, float* __restrict__ osq_s, int n){
  __shared__ __align__(16) uint16_t Al[64 * 128];
  __shared__ float csum[128], csq[128];
  __shared__ __align__(16) float ABl[256];
  int tid = threadIdx.x;
  int rbase = blockIdx.x * 64;
  int stripe = blockIdx.x & (NSTRIPE - 1);

  if (tid < 128){
    float s = 0.f, q = 0.f;
    #pragma unroll 8
    for (int st = 0; st < NSTRIPE; ++st){
      s += sin_s[st * 128 + tid];
      q += sqin_s[st * 128 + tid];
    }
    float mu = s * invN;
    float var = q * invN - mu * mu;
    float A = gin[tid] * rsqrtf(var + BN_EPS);
    ABl[tid] = A;
    ABl[128 + tid] = bein[tid] - mu * A;
    csum[tid] = 0.f; csq[tid] = 0.f;
  }
  __syncthreads();

  #pragma unroll
  for (int i = 0; i < 4; ++i){
    int f = tid + 256 * i;
    int m = f >> 4, c = f & 15;
    int gr = rbase + m;
    uint4 v = make_uint4(0, 0, 0, 0);
    if (gr < n){
      v = *(const uint4*)(Ag + (size_t)gr * 128 + c * 8);
      int k0 = c * 8;
      float4 ka0 = *(const float4*)(ABl + k0);
      float4 ka1 = *(const float4*)(ABl + k0 + 4);
      float4 kb0 = *(const float4*)(ABl + 128 + k0);
      float4 kb1 = *(const float4*)(ABl + 128 + k0 + 4);
      float e0 = fmaxf(fmaf(bflo2f(v.x), ka0.x, kb0.x), 0.f);
      float e1 = fmaxf(fmaf(bfhi2f(v.x), ka0.y, kb0.y), 0.f);
      float e2 = fmaxf(fmaf(bflo2f(v.y), ka0.z, kb0.z), 0.f);
      float e3 = fmaxf(fmaf(bfhi2f(v.y), ka0.w, kb0.w), 0.f);
      float e4 = fmaxf(fmaf(bflo2f(v.z), ka1.x, kb1.x), 0.f);
      float e5 = fmaxf(fmaf(bfhi2f(v.z), ka1.y, kb1.y), 0.f);
      float e6 = fmaxf(fmaf(bflo2f(v.w), ka1.z, kb1.z), 0.f);
      float e7 = fmaxf(fmaf(bfhi2f(v.w), ka1.w, kb1.w), 0.f);
      v.x = pack2(e0, e1); v.y = pack2(e2, e3);
      v.z = pack2(e4, e5); v.w = pack2(e6, e7);
    }
    *(uint4*)((char*)Al + m * 256 + ((c ^ (m & 15)) * 16)) = v;
  }
  __syncthreads();

  int lane = tid & 63;
  int w    = tid >> 6;
  int hi   = lane >> 5;
  int key  = lane & 15;
  int m0   = (w & 1) * 32;
  int n0   = (w >> 1) * 64;
  int mrow = m0 + (lane & 31);
  int nrow0 = n0 + (lane & 31);
  int nrow1 = nrow0 + 32;

  f32x16 acc0, acc1;
  #pragma unroll
  for (int i = 0; i < 16; ++i){ acc0[i] = 0.f; acc1[i] = 0.f; }

  const char* Ab = (const char*)Al;
  #pragma unroll
  for (int kt = 0; kt < 8; ++kt){
    int ck = 2 * kt + hi;
    bf16x8 a  = *(const bf16x8*)(Ab + mrow * 256 + ((ck ^ key) * 16));
    bf16x8 b0 = *(const bf16x8*)(Wt + nrow0 * 128 + ck * 8);
    bf16x8 b1 = *(const bf16x8*)(Wt + nrow1 * 128 + ck * 8);
    acc0 = __builtin_amdgcn_mfma_f32_32x32x16_bf16(a, b0, acc0, 0, 0, 0);
    acc1 = __builtin_amdgcn_mfma_f32_32x32x16_bf16(a, b1, acc1, 0, 0, 0);
  }
  __syncthreads();

  uint16_t* Yl = Al;
  float bias0 = bias_f[nrow0];
  float bias1 = bias_f[nrow1];
  float ps0 = 0.f, pq0 = 0.f, ps1 = 0.f, pq1 = 0.f;
  #pragma unroll
  for (int r = 0; r < 16; ++r){
    int row = m0 + (r & 3) + 8 * (r >> 2) + 4 * hi;
    bool valid = (rbase + row) < n;
    float y0 = acc0[r] + bias0;
    float y1 = acc1[r] + bias1;
    if (valid){
      ps0 += y0; pq0 += y0 * y0;
      ps1 += y1; pq1 += y1 * y1;
    }
    Yl[row * 128 + nrow0] = f2bf(y0);
    Yl[row * 128 + nrow1] = f2bf(y1);
  }
  atomicAdd(&csum[nrow0], ps0); atomicAdd(&csq[nrow0], pq0);
  atomicAdd(&csum[nrow1], ps1); atomicAdd(&csq[nrow1], pq1);
  __syncthreads();

  #pragma unroll
  for (int i = 0; i < 4; ++i){
    int id = tid + 256 * i;
    int row = id >> 4, cc = id & 15;
    int gr = rbase + row;
    if (gr < n)
      *((uint4*)Yout + (size_t)gr * 16 + cc) = *((const uint4*)Yl + id);
  }
  if (tid < 128){
    atomicAdd(&osum_s[stripe * 128 + tid], csum[tid]);
    atomicAdd(&osq_s[stripe * 128 + tid], csq[tid]);
  }
}

// -------- reduce BN2 stripes -> AB2 (one block) --------
__global__ void k_bncoef2(const float* __restrict__ sum_s, const float* __restrict__ sq_s,
                          const float* __restrict__ g, const float* __restrict__ be,
                          float* __restrict__ AB, float invN){
  int c = threadIdx.x;
  if (c < 128){
    float s = 0.f, q = 0.f;
    #pragma unroll 8
    for (int st = 0; st < NSTRIPE; ++st){
      s += sum_s[st * 128 + c];
      q += sq_s[st * 128 + c];
    }
    float mu = s * invN;
    float var = q * invN - mu * mu;
    float A = g[c] * rsqrtf(var + BN_EPS);
    AB[c] = A;
    AB[128 + c] = be[c] - mu * A;
  }
}

// -------- final: BN+ReLU via precomputed AB, fp32 out --------
__global__ void k_final(const uint16_t* __restrict__ Y2b, const float* __restrict__ ABg,
                        float* __restrict__ out, int total){
  __shared__ __align__(16) float AB[256];
  int tid = threadIdx.x;
  if (tid < 64){
    *(float4*)(AB + tid * 4) = *(const float4*)(ABg + tid * 4);
  }
  __syncthreads();
  int i = (blockIdx.x * 256 + tid) * 4;
  if (i >= total) return;
  uint2 v = *(const uint2*)(Y2b + i);
  int c = i & 127;
  float4 a = *(const float4*)(AB + c);
  float4 b = *(const float4*)(AB + 128 + c);
  float4 o;
  o.x = fmaxf(fmaf(bflo2f(v.x), a.x, b.x), 0.f);
  o.y = fmaxf(fmaf(bfhi2f(v.x), a.y, b.y), 0.f);
  o.z = fmaxf(fmaf(bflo2f(v.y), a.z, b.z), 0.f);
  o.w = fmaxf(fmaf(bfhi2f(v.y), a.w, b.w), 0.f);
  *(float4*)(out + i) = o;
}

extern "C" void kernel_launch(void* const* d_in, const int* in_sizes, int n_in,
                              void* d_out, int out_size, void* d_ws, size_t ws_size,
                              hipStream_t stream){
  const float* h    = (const float*)d_in[0];
  const int*   esrc = (const int*)d_in[1];
  const int*   edst = (const int*)d_in[2];
  const float* W1   = (const float*)d_in[3];
  const float* b1   = (const float*)d_in[4];
  const float* g1   = (const float*)d_in[5];
  const float* be1  = (const float*)d_in[6];
  const float* W2   = (const float*)d_in[7];
  const float* b2   = (const float*)d_in[8];
  const float* g2   = (const float*)d_in[9];
  const float* be2  = (const float*)d_in[10];
  const float* eps  = (const float*)d_in[11];
  int n = in_sizes[0] / 128;
  int E = in_sizes[1];
  (void)n_in; (void)out_size; (void)ws_size;

  int NB = (n + 255) >> 8;
  int EB = (E + 4095) >> 12;

  char* ws = (char*)d_ws;
  size_t off = 0;
  auto alloc = [&](size_t bytes) -> void* {
    void* p = ws + off;
    off += (bytes + 511) & ~(size_t)511;
    return p;
  };
  size_t feat_b = (size_t)n * 128 * 2;
  uint16_t* B1   = (uint16_t*)alloc(feat_b);        // hb (live through k_gg) -> Y2b
  uint16_t* B2   = (uint16_t*)alloc(feat_b);        // binned (dead after csr) -> Y1b
  int*   row_off = (int*)alloc((size_t)(n + 1) * 4);
  int*   col_idx = (int*)alloc((size_t)E * 4);
  int*   M       = (int*)alloc((size_t)EB * NB * 4);
  int*   btot    = (int*)alloc((size_t)(NB + 1) * 4);
  int*   bbase   = (int*)alloc((size_t)(NB + 1) * 4);
  float* stats   = (float*)alloc((size_t)4 * NSTRIPE * 128 * 4);
  float* AB2     = (float*)alloc(256 * 4);
  uint16_t* Wt1  = (uint16_t*)alloc(128 * 128 * 2);
  uint16_t* Wt2  = (uint16_t*)alloc(128 * 128 * 2);
  float* sum1 = stats;
  float* sq1  = stats + NSTRIPE * 128;
  float* sum2 = stats + 2 * NSTRIPE * 128;
  float* sq2  = stats + 3 * NSTRIPE * 128;
  uint16_t* hb  = B1;
  uint32_t* binned = (uint32_t*)B2;
  uint16_t* Y1b = B2;   // overwrites binned (dead)
  uint16_t* Y2b = B1;   // overwrites hb (dead after k_gg)

  int total = n * 128;
  int hblocks = total / 8 / 256;
  float invN = 1.0f / (float)n;

  k_prep<<<hblocks + 16 + EB, 256, 0, stream>>>(h, hb, hblocks, W1, W2, Wt1, Wt2,
                                                stats, edst, M, E, NB);
  k_colscan<<<NB, 256, 0, stream>>>(M, btot, EB, NB);
  k_bscan  <<<1, 256, 0, stream>>>(btot, bbase, row_off, NB, n, E);
  k_bin    <<<EB, 256, 0, stream>>>(esrc, edst, M, bbase, binned, E, NB);
  k_csr    <<<NB, 256, 0, stream>>>(binned, bbase, row_off, col_idx, n);

  int gblocks = (n + 63) / 64;
  k_gg<<<gblocks, 256, 0, stream>>>(hb, row_off, col_idx, eps, Wt1, b1,
                                    Y1b, sum1, sq1, n);
  k_mgemm2<<<gblocks, 256, 0, stream>>>(Y1b, Wt2, b2,
      sum1, sq1, g1, be1, invN, Y2b, sum2, sq2, n);

  k_bncoef2<<<1, 128, 0, stream>>>(sum2, sq2, g2, be2, AB2, invN);
  k_final<<<(total / 4 + 255) / 256, 256, 0, stream>>>(Y2b, AB2, (float*)d_out, total);
}